// Round 6
// baseline (74.949 us; speedup 1.0000x reference)
//
#include <hip/hip_runtime.h>
#include <stdint.h>

#define M_BOXES 8192
#define MIN_CONF_F 0.25f
#define MIN_IOU_F 0.45f
#define VCAP 640          // ~19 sigma above E[valid]=307
#define NW 10             // VCAP/64 words per suppression row

typedef unsigned long long u64;
typedef unsigned int u32;

// ws layout (bytes)
#define WS_WCNT   0        // int[128]
#define WS_V      512      // int
#define WS_VKEYS  1024     // u64[8192] chunk-compacted keys
#define WS_SKEY   66560    // u64[VCAP]
#define WS_SBOX   71680    // float4[VCAP]
#define WS_SAREA  81920    // float[VCAP]
#define WS_SUP    84480    // u64[VCAP*NW]
#define WS_NEED   135680

__device__ inline float scalar_to_float(const int* p) {
    int v = p[0];
    if (v > 0 && v < (1 << 20)) return (float)v;   // plain int
    return __int_as_float(v);                      // float bit-pattern
}

__device__ inline u64 rl64(u64 v, int b) {
    u32 lo = (u32)__builtin_amdgcn_readlane((int)(u32)v, b);
    u32 hi = (u32)__builtin_amdgcn_readlane((int)(u32)(v >> 32), b);
    return ((u64)hi << 32) | lo;
}

__device__ inline u64 wave_or64(u64 v) {
    #pragma unroll
    for (int o = 32; o > 0; o >>= 1) {
        int lo = __shfl_xor((int)(u32)v, o, 64);
        int hi = __shfl_xor((int)(u32)(v >> 32), o, 64);
        v |= ((u64)(u32)hi << 32) | (u32)lo;
    }
    return v;
}

// ---------------- k1: fill output + gather + wave-ballot chunk compact ----
__global__ __launch_bounds__(128) void k1_fill_gather(
    const float* __restrict__ scores, const int* __restrict__ indices,
    float* __restrict__ out, u64* __restrict__ vkeys, int* __restrict__ wcnt)
{
    int i = blockIdx.x * 128 + threadIdx.x;        // grid covers exactly 8192
    int cls = indices[3 * i + 1];
    int idx = indices[3 * i + 2];
    float conf = scores[cls * M_BOXES + idx];
    *reinterpret_cast<float4*>(out + 4 * i) = make_float4(0.f, 0.f, 0.f, 0.f);
    out[4 * M_BOXES + i] = 0.f;
    out[5 * M_BOXES + i] = (float)cls;
    out[6 * M_BOXES + i] = 0.f;
    bool valid = (conf > MIN_CONF_F) &&
                 (cls == 2 || cls == 3 || cls == 5 || cls == 7);
    u64 mask = __ballot(valid);
    int lane = threadIdx.x & 63;
    int wid = i >> 6;
    if (valid) {
        int pos = (int)__popcll(mask & ((1ull << lane) - 1ull));
        // key: conf desc, orig asc (JAX stable argsort(-s)); idx in low bits
        u64 key = ((u64)(~__float_as_uint(conf)) << 32)
                | ((u64)(u32)i << 13) | (u64)(u32)idx;
        vkeys[(wid << 6) + pos] = key;
    }
    if (lane == 0) wcnt[wid] = (int)__popcll(mask);
}

// ---------------- k2: wide rank-sort (redundant assembly per block) -------
__global__ __launch_bounds__(64) void k2_sort(
    const float* __restrict__ boxes_raw, const int* __restrict__ p_out_h,
    const int* __restrict__ p_out_w, const u64* __restrict__ vkeys,
    const int* __restrict__ wcnt, int* __restrict__ pV,
    u64* __restrict__ skey, float4* __restrict__ sbox,
    float* __restrict__ sarea)
{
    __shared__ int cnt_s[128], pre_s[128];
    __shared__ u64 tkey[VCAP];
    int lane = threadIdx.x;
    int cA = wcnt[lane], cB = wcnt[64 + lane];
    int sA = cA, sB = cB;
    #pragma unroll
    for (int o = 1; o < 64; o <<= 1) {
        int t = __shfl_up(sA, o, 64); if (lane >= o) sA += t;
        int u = __shfl_up(sB, o, 64); if (lane >= o) sB += u;
    }
    int totA = __shfl(sA, 63, 64);
    int V = totA + __shfl(sB, 63, 64);
    if (V > VCAP) V = VCAP;
    cnt_s[lane] = cA;      cnt_s[64 + lane] = cB;
    pre_s[lane] = sA - cA; pre_s[64 + lane] = totA + sB - cB;
    __syncthreads();
    if (blockIdx.x == 0 && lane == 0) *pV = V;
    if ((int)(blockIdx.x * 64) >= V) return;

    // assemble compacted keys into LDS (deterministic positions)
    for (int w = 0; w < 128; ++w) {
        int c = cnt_s[w];
        if (lane < c) {
            int p = pre_s[w] + lane;
            if (p < VCAP) tkey[p] = vkeys[(w << 6) + lane];
        }
    }
    __syncthreads();

    int s = blockIdx.x * 64 + lane;
    if (s < V) {
        u64 k = tkey[s];
        int r = 0;
        #pragma unroll 4
        for (int j = 0; j < V; ++j) r += (tkey[j] < k) ? 1 : 0;
        int idx = (int)(k & 0x1FFFull);
        float4 b = *reinterpret_cast<const float4*>(boxes_raw + 4 * idx); // y1,x1,y2,x2
        float W = scalar_to_float(p_out_w);
        float H = scalar_to_float(p_out_h);
        float4 c4;
        c4.x = fminf(fmaxf(b.y, 0.f), W);
        c4.y = fminf(fmaxf(b.x, 0.f), H);
        c4.z = fminf(fmaxf(b.w, 0.f), W);
        c4.w = fminf(fmaxf(b.z, 0.f), H);
        skey[r] = k;
        sbox[r] = c4;
        sarea[r] = fmaxf(c4.z - c4.x, 0.f) * fmaxf(c4.w - c4.y, 0.f);
    }
}

// ---------------- k3: suppression bit-matrix, one task per wave -----------
__global__ __launch_bounds__(256) void k3_matrix(
    const float4* __restrict__ sbox, const float* __restrict__ sarea,
    const int* __restrict__ pV, u64* __restrict__ sup)
{
    int V = *pV;
    int wave = (blockIdx.x * 256 + threadIdx.x) >> 6;
    int lane = threadIdx.x & 63;
    int bi = wave / NW;            // constant divisor -> magic mul
    int w = wave - bi * NW;
    int i0 = bi << 3;
    int nw = (V + 63) >> 6;
    if (i0 >= V || w >= nw) return;
    int j = (w << 6) + lane;
    bool jv = j < V;
    float4 bj = jv ? sbox[j] : make_float4(0.f, 0.f, 0.f, 0.f);
    float aj = jv ? sarea[j] : 0.f;
    int rend = V - i0; if (rend > 8) rend = 8;
    for (int r = 0; r < rend; ++r) {
        int i = i0 + r;
        float4 bi4 = sbox[i];          // uniform
        float ai = sarea[i];           // uniform
        bool p = false;
        if (jv && j > i) {
            float ix1 = fmaxf(bi4.x, bj.x);
            float iy1 = fmaxf(bi4.y, bj.y);
            float ix2 = fminf(bi4.z, bj.z);
            float iy2 = fminf(bi4.w, bj.w);
            float inter = fmaxf(ix2 - ix1, 0.f) * fmaxf(iy2 - iy1, 0.f);
            float iou = inter / (ai + aj - inter + 1e-9f);   // IEEE div, matches ref
            p = iou > MIN_IOU_F;
        }
        u64 bits = __ballot(p);
        if (lane == 0) sup[i * NW + w] = bits;
    }
}

// ---------------- k4: single-wave branchless scan + scatter ---------------
__global__ __launch_bounds__(64) void k4_scan_scatter(
    float* __restrict__ out, const u64* __restrict__ skey,
    const float4* __restrict__ sbox, const int* __restrict__ pV,
    const u64* __restrict__ supG)
{
    int lane = threadIdx.x;
    int V = *pV;
    if (V <= 0) return;
    int nw = (V + 63) >> 6;

    u64 live[NW], supp[NW];
    #pragma unroll
    for (int w = 0; w < NW; ++w) {
        int c = V - (w << 6);
        live[w] = (c >= 64) ? ~0ull : (c > 0 ? ((1ull << c) - 1ull) : 0ull);
        supp[w] = 0ull;
    }

    u64 rowA[NW], rowB[NW];
    {   // load chunk 0 rows
        bool rv = lane < V;
        #pragma unroll
        for (int w = 0; w < NW; ++w)
            rowA[w] = (rv && w < nw) ? supG[lane * NW + w] : 0ull;
    }

    auto step = [&](u64 (&rc)[NW], u64 (&rn)[NW], int ci) {
        // prefetch chunk ci+1 (words >= ci+1 only)
        int rI = ((ci + 1) << 6) + lane;
        bool rv = (ci + 1) < nw && rI < V;
        #pragma unroll
        for (int w = 0; w < NW; ++w)
            rn[w] = (rv && w >= ci + 1 && w < nw) ? supG[rI * NW + w] : 0ull;
        // select diagonal word + init (static reg indices, runtime guard)
        u64 rw = 0, cur = 0;
        #pragma unroll
        for (int w = 0; w < NW; ++w)
            if (w == ci) { rw = rc[w]; cur = live[w] & ~supp[w]; }
        // 64-step branchless in-word recurrence
        #pragma unroll
        for (int b = 0; b < 64; ++b) {
            u64 rb = rl64(rw, b);
            u64 nxt = cur & ~rb;            // row has only bits > b
            cur = ((cur >> b) & 1ull) ? nxt : cur;
        }
        #pragma unroll
        for (int w = 0; w < NW; ++w) if (w == ci) live[w] = cur;
        // cross-word suppression, once per future word
        #pragma unroll
        for (int w2 = 0; w2 < NW; ++w2)
            if (w2 > ci && w2 < nw) {
                u64 mine = ((cur >> lane) & 1ull) ? rc[w2] : 0ull;
                supp[w2] |= wave_or64(mine);
            }
    };

    int ci = 0;
    while (ci < nw) {
        step(rowA, rowB, ci); ++ci;
        if (ci < nw) { step(rowB, rowA, ci); ++ci; }
    }

    // scatter kept entries
    #pragma unroll
    for (int ii = 0; ii < NW; ++ii) {
        int s = (ii << 6) + lane;
        if ((ii << 6) < V && s < V && ((live[ii] >> lane) & 1ull)) {
            u64 k = skey[s];
            u32 orig = (u32)((k >> 13) & 0x1FFFull);
            float conf = __uint_as_float(~(u32)(k >> 32));   // exact roundtrip
            float4 b = sbox[s];
            *reinterpret_cast<float4*>(out + 4 * orig) = b;
            out[4 * M_BOXES + orig] = conf;
            out[6 * M_BOXES + orig] = 1.0f;
        }
    }
}

// ---------------- fallback (small ws): R5 path, atomic compaction ---------
__global__ __launch_bounds__(256) void fb_gather(
    const float* __restrict__ boxes_raw, const float* __restrict__ scores,
    const int* __restrict__ indices, const int* __restrict__ p_out_h,
    const int* __restrict__ p_out_w, float* __restrict__ out,
    u64* __restrict__ vkeys, float4* __restrict__ vboxes,
    int* __restrict__ vcount)
{
    int i = blockIdx.x * blockDim.x + threadIdx.x;
    if (i >= M_BOXES) return;
    int cls = indices[3 * i + 1];
    int idx = indices[3 * i + 2];
    float conf = scores[cls * M_BOXES + idx];
    *reinterpret_cast<float4*>(out + 4 * i) = make_float4(0.f, 0.f, 0.f, 0.f);
    out[4 * M_BOXES + i] = 0.f;
    out[5 * M_BOXES + i] = (float)cls;
    out[6 * M_BOXES + i] = 0.f;
    bool valid = (conf > MIN_CONF_F) &&
                 (cls == 2 || cls == 3 || cls == 5 || cls == 7);
    if (valid) {
        float4 b = *reinterpret_cast<const float4*>(boxes_raw + 4 * idx);
        float W = scalar_to_float(p_out_w);
        float H = scalar_to_float(p_out_h);
        float4 c;
        c.x = fminf(fmaxf(b.y, 0.f), W);
        c.y = fminf(fmaxf(b.x, 0.f), H);
        c.z = fminf(fmaxf(b.w, 0.f), W);
        c.w = fminf(fmaxf(b.z, 0.f), H);
        int p = atomicAdd(vcount, 1);
        if (p < VCAP) {
            vkeys[p] = ((u64)(~__float_as_uint(conf)) << 32) | (u32)i;
            vboxes[p] = c;
        }
    }
}

__global__ __launch_bounds__(1024) void fb_nms(
    float* __restrict__ out, const u64* __restrict__ vkeys,
    const float4* __restrict__ vboxes, const int* __restrict__ vcount)
{
    __shared__ u64 tkey[VCAP];
    __shared__ u64 skey[VCAP];
    __shared__ float4 sbox[VCAP];
    __shared__ unsigned char keepb[VCAP];
    int tid = threadIdx.x;
    int V = *vcount;
    if (V > VCAP) V = VCAP;
    if (V <= 0) return;
    for (int s = tid; s < V; s += 1024) tkey[s] = vkeys[s];
    __syncthreads();
    for (int s = tid; s < V; s += 1024) {
        u64 k = tkey[s];
        int r = 0;
        for (int j = 0; j < V; ++j) r += (tkey[j] < k);
        skey[r] = k;
        sbox[r] = vboxes[s];
    }
    __syncthreads();
    for (int s = tid; s < V; s += 1024) keepb[s] = 1;
    __syncthreads();
    for (int i = 0; i < V; ++i) {
        if (keepb[i]) {
            float4 bi = sbox[i];
            float ai = fmaxf(bi.z - bi.x, 0.f) * fmaxf(bi.w - bi.y, 0.f);
            for (int s = i + 1 + tid; s < V; s += 1024) {
                if (keepb[s]) {
                    float4 bj = sbox[s];
                    float aj = fmaxf(bj.z - bj.x, 0.f) * fmaxf(bj.w - bj.y, 0.f);
                    float ix1 = fmaxf(bi.x, bj.x);
                    float iy1 = fmaxf(bi.y, bj.y);
                    float ix2 = fminf(bi.z, bj.z);
                    float iy2 = fminf(bi.w, bj.w);
                    float inter = fmaxf(ix2 - ix1, 0.f) * fmaxf(iy2 - iy1, 0.f);
                    float iou = inter / (ai + aj - inter + 1e-9f);
                    if (iou > MIN_IOU_F) keepb[s] = 0;
                }
            }
        }
        __syncthreads();
    }
    for (int s = tid; s < V; s += 1024) {
        if (keepb[s]) {
            u64 k = skey[s];
            u32 orig = (u32)(k & 0xFFFFFFFFull);
            float conf = __uint_as_float(~(u32)(k >> 32));
            float4 b = sbox[s];
            *reinterpret_cast<float4*>(out + 4 * orig) = b;
            out[4 * M_BOXES + orig] = conf;
            out[6 * M_BOXES + orig] = 1.0f;
        }
    }
}

extern "C" void kernel_launch(void* const* d_in, const int* in_sizes, int n_in,
                              void* d_out, int out_size, void* d_ws, size_t ws_size,
                              hipStream_t stream) {
    const float* boxes_raw = (const float*)d_in[0];
    const float* scores    = (const float*)d_in[1];
    const int*   indices   = (const int*)d_in[2];
    const int*   p_out_h   = (const int*)d_in[3];
    const int*   p_out_w   = (const int*)d_in[4];
    float* out = (float*)d_out;
    char* ws = (char*)d_ws;

    if (ws_size >= WS_NEED) {
        int*    wcnt  = (int*)(ws + WS_WCNT);
        int*    pV    = (int*)(ws + WS_V);
        u64*    vkeys = (u64*)(ws + WS_VKEYS);
        u64*    skey  = (u64*)(ws + WS_SKEY);
        float4* sbox  = (float4*)(ws + WS_SBOX);
        float*  sarea = (float*)(ws + WS_SAREA);
        u64*    sup   = (u64*)(ws + WS_SUP);

        k1_fill_gather<<<M_BOXES / 128, 128, 0, stream>>>(
            scores, indices, out, vkeys, wcnt);
        k2_sort<<<VCAP / 64, 64, 0, stream>>>(
            boxes_raw, p_out_h, p_out_w, vkeys, wcnt, pV, skey, sbox, sarea);
        k3_matrix<<<(VCAP / 8) * NW / 4, 256, 0, stream>>>(
            sbox, sarea, pV, sup);
        k4_scan_scatter<<<1, 64, 0, stream>>>(out, skey, sbox, pV, sup);
    } else {
        int*    vcount = (int*)ws;
        u64*    vkeys  = (u64*)(ws + 16);
        float4* vboxes = (float4*)(ws + 16 + VCAP * sizeof(u64));
        hipMemsetAsync(d_ws, 0, 16, stream);
        fb_gather<<<M_BOXES / 256, 256, 0, stream>>>(
            boxes_raw, scores, indices, p_out_h, p_out_w, out,
            vkeys, vboxes, vcount);
        fb_nms<<<1, 1024, 0, stream>>>(out, vkeys, vboxes, vcount);
    }
}

// Round 7
// 44.121 us; speedup vs baseline: 1.6987x; 1.6987x over previous
//
#include <hip/hip_runtime.h>
#include <stdint.h>

#define M_BOXES 8192
#define MIN_CONF_F 0.25f
#define MIN_IOU_F 0.45f
#define VCAP 640          // ~19 sigma above E[valid]=307
#define NW 10             // VCAP/64 words per suppression row

typedef unsigned long long u64;
typedef unsigned int u32;

// ws layout (bytes)
#define WS_DONE   0        // int[2]: done counters for kA, kB
#define WS_V      8        // int
#define WS_WCNT   64       // int[128]
#define WS_VKEYS  1024     // u64[8192] chunk-compacted keys
#define WS_SKEY   66560    // u64[VCAP]
#define WS_SBOX   71680    // float4[VCAP]
#define WS_SAREA  81920    // float[VCAP]
#define WS_SUP    84480    // u64[VCAP*NW]
#define WS_NEED   135680

__device__ inline float scalar_to_float(const int* p) {
    int v = p[0];
    if (v > 0 && v < (1 << 20)) return (float)v;   // plain int
    return __int_as_float(v);                      // float bit-pattern
}

__device__ inline u64 rl64(u64 v, int b) {
    u32 lo = (u32)__builtin_amdgcn_readlane((int)(u32)v, b);
    u32 hi = (u32)__builtin_amdgcn_readlane((int)(u32)(v >> 32), b);
    return ((u64)hi << 32) | lo;
}

__device__ inline u64 wave_or64(u64 v) {
    #pragma unroll
    for (int o = 32; o > 0; o >>= 1) {
        int lo = __shfl_xor((int)(u32)v, o, 64);
        int hi = __shfl_xor((int)(u32)(v >> 32), o, 64);
        v |= ((u64)(u32)hi << 32) | (u32)lo;
    }
    return v;
}

// ---- kA: fill + gather + wave-ballot compact; last block sorts -----------
__global__ __launch_bounds__(512) void kA_gather_sort(
    const float* __restrict__ boxes_raw, const float* __restrict__ scores,
    const int* __restrict__ indices, const int* __restrict__ p_out_h,
    const int* __restrict__ p_out_w, float* __restrict__ out,
    u64* __restrict__ vkeys, int* __restrict__ wcnt, int* __restrict__ done,
    int* __restrict__ pV, u64* __restrict__ skey, float4* __restrict__ sbox,
    float* __restrict__ sarea)
{
    __shared__ int pre_s[129];
    __shared__ u64 tkey[VCAP];
    __shared__ int amLast;

    int tid = threadIdx.x;
    int i = blockIdx.x * 512 + tid;                // grid covers exactly 8192
    int cls = indices[3 * i + 1];
    int idx = indices[3 * i + 2];
    float conf = scores[cls * M_BOXES + idx];
    *reinterpret_cast<float4*>(out + 4 * i) = make_float4(0.f, 0.f, 0.f, 0.f);
    out[4 * M_BOXES + i] = 0.f;
    out[5 * M_BOXES + i] = (float)cls;
    out[6 * M_BOXES + i] = 0.f;
    bool valid = (conf > MIN_CONF_F) &&
                 (cls == 2 || cls == 3 || cls == 5 || cls == 7);
    u64 mask = __ballot(valid);
    int lane = tid & 63;
    int wid = i >> 6;
    if (valid) {
        int pos = (int)__popcll(mask & ((1ull << lane) - 1ull));
        // key: [~conf:32][i:13][idx:13] -> conf desc, i asc (stable argsort)
        u64 key = ((u64)(~__float_as_uint(conf)) << 32)
                | ((u64)(u32)i << 13) | (u64)(u32)idx;
        vkeys[(wid << 6) + pos] = key;
    }
    if (lane == 0) wcnt[wid] = (int)__popcll(mask);

    __syncthreads();
    if (tid == 0) {
        __threadfence();                            // release our writes
        int p = atomicAdd(&done[0], 1);
        amLast = (p == (int)gridDim.x - 1);
    }
    __syncthreads();
    if (!amLast) return;                            // whole block uniform
    __threadfence();                                // acquire others' writes

    // prefix over 128 wave counts (two-halves shuffle scan on wave 0)
    if (tid < 64) {
        int cA = wcnt[tid], cB = wcnt[64 + tid];
        int sA = cA, sB = cB;
        #pragma unroll
        for (int o = 1; o < 64; o <<= 1) {
            int t = __shfl_up(sA, o, 64); if (tid >= o) sA += t;
            int u = __shfl_up(sB, o, 64); if (tid >= o) sB += u;
        }
        int totA = __shfl(sA, 63, 64);
        int totB = __shfl(sB, 63, 64);
        pre_s[tid] = sA - cA;
        pre_s[64 + tid] = totA + sB - cB;
        if (tid == 0) pre_s[128] = totA + totB;
    }
    __syncthreads();
    int V = pre_s[128];
    if (V > VCAP) V = VCAP;
    if (tid == 0) *pV = V;

    // assembly: one independent, pipelined global load per slot (bin search)
    for (int s = tid; s < V; s += 512) {
        int lo = 0, hi = 128;
        #pragma unroll
        for (int st = 0; st < 7; ++st) {
            int mid = (lo + hi) >> 1;
            if (pre_s[mid] <= s) lo = mid; else hi = mid;
        }
        tkey[s] = vkeys[(lo << 6) + (s - pre_s[lo])];
    }
    __syncthreads();

    // rank sort (unique keys -> permutation); gather + clip box per slot
    float W = scalar_to_float(p_out_w);
    float H = scalar_to_float(p_out_h);
    for (int s = tid; s < V; s += 512) {
        u64 k = tkey[s];
        int r = 0;
        #pragma unroll 4
        for (int j = 0; j < V; ++j) r += (tkey[j] < k) ? 1 : 0;
        int bidx = (int)(k & 0x1FFFull);
        float4 b = *reinterpret_cast<const float4*>(boxes_raw + 4 * bidx); // y1,x1,y2,x2
        float4 c4;
        c4.x = fminf(fmaxf(b.y, 0.f), W);
        c4.y = fminf(fmaxf(b.x, 0.f), H);
        c4.z = fminf(fmaxf(b.w, 0.f), W);
        c4.w = fminf(fmaxf(b.z, 0.f), H);
        skey[r] = k;
        sbox[r] = c4;
        sarea[r] = fmaxf(c4.z - c4.x, 0.f) * fmaxf(c4.w - c4.y, 0.f);
    }
}

// ---- kB: suppression bit-matrix (one task/wave); last block scans --------
__global__ __launch_bounds__(512) void kB_matrix_scan(
    float* __restrict__ out, const u64* __restrict__ skey,
    const float4* __restrict__ sbox, const float* __restrict__ sarea,
    const int* __restrict__ pV, u64* __restrict__ sup, int* __restrict__ done)
{
    __shared__ int amLast;
    int tid = threadIdx.x;
    int V = *pV;
    int nw = (V + 63) >> 6;
    int wave = blockIdx.x * 8 + (tid >> 6);
    int lane = tid & 63;
    int bi = wave / NW;                 // constant divisor
    int w = wave - bi * NW;
    int i0 = bi << 3;
    if (i0 < V && w < nw) {
        int j = (w << 6) + lane;
        bool jv = j < V;
        float4 bj = jv ? sbox[j] : make_float4(0.f, 0.f, 0.f, 0.f);
        float aj = jv ? sarea[j] : 0.f;
        int rend = V - i0; if (rend > 8) rend = 8;
        for (int r = 0; r < rend; ++r) {
            int i = i0 + r;
            float4 bi4 = sbox[i];       // uniform
            float ai = sarea[i];        // uniform
            bool p = false;
            if (jv && j > i) {
                float ix1 = fmaxf(bi4.x, bj.x);
                float iy1 = fmaxf(bi4.y, bj.y);
                float ix2 = fminf(bi4.z, bj.z);
                float iy2 = fminf(bi4.w, bj.w);
                float inter = fmaxf(ix2 - ix1, 0.f) * fmaxf(iy2 - iy1, 0.f);
                float iou = inter / (ai + aj - inter + 1e-9f);  // IEEE div
                p = iou > MIN_IOU_F;
            }
            u64 bits = __ballot(p);
            if (lane == 0) sup[i * NW + w] = bits;
        }
    }
    __syncthreads();
    if (tid == 0) {
        __threadfence();
        int p = atomicAdd(&done[1], 1);
        amLast = (p == (int)gridDim.x - 1);
    }
    __syncthreads();
    if (!amLast) return;
    __threadfence();

    if (tid < 64 && V > 0) {
        u64 live[NW], supp[NW];
        #pragma unroll
        for (int ww = 0; ww < NW; ++ww) {
            int c = V - (ww << 6);
            live[ww] = (c >= 64) ? ~0ull : (c > 0 ? ((1ull << c) - 1ull) : 0ull);
            supp[ww] = 0ull;
        }
        u64 rowA[NW], rowB[NW];
        {
            bool rv = lane < V;
            #pragma unroll
            for (int ww = 0; ww < NW; ++ww)
                rowA[ww] = (rv && ww < nw) ? sup[lane * NW + ww] : 0ull;
        }
        auto step = [&](u64 (&rc)[NW], u64 (&rn)[NW], int ci) {
            int rI = ((ci + 1) << 6) + lane;
            bool rv = (ci + 1) < nw && rI < V;
            #pragma unroll
            for (int ww = 0; ww < NW; ++ww)
                rn[ww] = (rv && ww >= ci + 1 && ww < nw) ? sup[rI * NW + ww] : 0ull;
            u64 rw = 0, cur = 0;
            #pragma unroll
            for (int ww = 0; ww < NW; ++ww)
                if (ww == ci) { rw = rc[ww]; cur = live[ww] & ~supp[ww]; }
            #pragma unroll
            for (int b = 0; b < 64; ++b) {
                u64 rb = rl64(rw, b);
                u64 nxt = cur & ~rb;            // row has only bits > b
                cur = ((cur >> b) & 1ull) ? nxt : cur;
            }
            #pragma unroll
            for (int ww = 0; ww < NW; ++ww) if (ww == ci) live[ww] = cur;
            #pragma unroll
            for (int w2 = 0; w2 < NW; ++w2)
                if (w2 > ci && w2 < nw) {
                    u64 mine = ((cur >> lane) & 1ull) ? rc[w2] : 0ull;
                    supp[w2] |= wave_or64(mine);
                }
        };
        int ci = 0;
        while (ci < nw) {
            step(rowA, rowB, ci); ++ci;
            if (ci < nw) { step(rowB, rowA, ci); ++ci; }
        }
        // scatter kept entries
        #pragma unroll
        for (int ii = 0; ii < NW; ++ii) {
            int s = (ii << 6) + lane;
            if ((ii << 6) < V && s < V && ((live[ii] >> lane) & 1ull)) {
                u64 k = skey[s];
                u32 orig = (u32)((k >> 13) & 0x1FFFull);
                float conf = __uint_as_float(~(u32)(k >> 32)); // exact roundtrip
                float4 b = sbox[s];
                *reinterpret_cast<float4*>(out + 4 * orig) = b;
                out[4 * M_BOXES + orig] = conf;
                out[6 * M_BOXES + orig] = 1.0f;
            }
        }
    }
}

// ---------------- fallback (small ws): atomic compaction path -------------
__global__ __launch_bounds__(256) void fb_gather(
    const float* __restrict__ boxes_raw, const float* __restrict__ scores,
    const int* __restrict__ indices, const int* __restrict__ p_out_h,
    const int* __restrict__ p_out_w, float* __restrict__ out,
    u64* __restrict__ vkeys, float4* __restrict__ vboxes,
    int* __restrict__ vcount)
{
    int i = blockIdx.x * blockDim.x + threadIdx.x;
    if (i >= M_BOXES) return;
    int cls = indices[3 * i + 1];
    int idx = indices[3 * i + 2];
    float conf = scores[cls * M_BOXES + idx];
    *reinterpret_cast<float4*>(out + 4 * i) = make_float4(0.f, 0.f, 0.f, 0.f);
    out[4 * M_BOXES + i] = 0.f;
    out[5 * M_BOXES + i] = (float)cls;
    out[6 * M_BOXES + i] = 0.f;
    bool valid = (conf > MIN_CONF_F) &&
                 (cls == 2 || cls == 3 || cls == 5 || cls == 7);
    if (valid) {
        float4 b = *reinterpret_cast<const float4*>(boxes_raw + 4 * idx);
        float W = scalar_to_float(p_out_w);
        float H = scalar_to_float(p_out_h);
        float4 c;
        c.x = fminf(fmaxf(b.y, 0.f), W);
        c.y = fminf(fmaxf(b.x, 0.f), H);
        c.z = fminf(fmaxf(b.w, 0.f), W);
        c.w = fminf(fmaxf(b.z, 0.f), H);
        int p = atomicAdd(vcount, 1);
        if (p < VCAP) {
            vkeys[p] = ((u64)(~__float_as_uint(conf)) << 32) | (u32)i;
            vboxes[p] = c;
        }
    }
}

__global__ __launch_bounds__(1024) void fb_nms(
    float* __restrict__ out, const u64* __restrict__ vkeys,
    const float4* __restrict__ vboxes, const int* __restrict__ vcount)
{
    __shared__ u64 tkey[VCAP];
    __shared__ u64 skey[VCAP];
    __shared__ float4 sbox[VCAP];
    __shared__ unsigned char keepb[VCAP];
    int tid = threadIdx.x;
    int V = *vcount;
    if (V > VCAP) V = VCAP;
    if (V <= 0) return;
    for (int s = tid; s < V; s += 1024) tkey[s] = vkeys[s];
    __syncthreads();
    for (int s = tid; s < V; s += 1024) {
        u64 k = tkey[s];
        int r = 0;
        for (int j = 0; j < V; ++j) r += (tkey[j] < k);
        skey[r] = k;
        sbox[r] = vboxes[s];
    }
    __syncthreads();
    for (int s = tid; s < V; s += 1024) keepb[s] = 1;
    __syncthreads();
    for (int i = 0; i < V; ++i) {
        if (keepb[i]) {
            float4 bi = sbox[i];
            float ai = fmaxf(bi.z - bi.x, 0.f) * fmaxf(bi.w - bi.y, 0.f);
            for (int s = i + 1 + tid; s < V; s += 1024) {
                if (keepb[s]) {
                    float4 bj = sbox[s];
                    float aj = fmaxf(bj.z - bj.x, 0.f) * fmaxf(bj.w - bj.y, 0.f);
                    float ix1 = fmaxf(bi.x, bj.x);
                    float iy1 = fmaxf(bi.y, bj.y);
                    float ix2 = fminf(bi.z, bj.z);
                    float iy2 = fminf(bi.w, bj.w);
                    float inter = fmaxf(ix2 - ix1, 0.f) * fmaxf(iy2 - iy1, 0.f);
                    float iou = inter / (ai + aj - inter + 1e-9f);
                    if (iou > MIN_IOU_F) keepb[s] = 0;
                }
            }
        }
        __syncthreads();
    }
    for (int s = tid; s < V; s += 1024) {
        if (keepb[s]) {
            u64 k = skey[s];
            u32 orig = (u32)(k & 0xFFFFFFFFull);
            float conf = __uint_as_float(~(u32)(k >> 32));
            float4 b = sbox[s];
            *reinterpret_cast<float4*>(out + 4 * orig) = b;
            out[4 * M_BOXES + orig] = conf;
            out[6 * M_BOXES + orig] = 1.0f;
        }
    }
}

extern "C" void kernel_launch(void* const* d_in, const int* in_sizes, int n_in,
                              void* d_out, int out_size, void* d_ws, size_t ws_size,
                              hipStream_t stream) {
    const float* boxes_raw = (const float*)d_in[0];
    const float* scores    = (const float*)d_in[1];
    const int*   indices   = (const int*)d_in[2];
    const int*   p_out_h   = (const int*)d_in[3];
    const int*   p_out_w   = (const int*)d_in[4];
    float* out = (float*)d_out;
    char* ws = (char*)d_ws;

    if (ws_size >= WS_NEED) {
        int*    done  = (int*)(ws + WS_DONE);
        int*    pV    = (int*)(ws + WS_V);
        int*    wcnt  = (int*)(ws + WS_WCNT);
        u64*    vkeys = (u64*)(ws + WS_VKEYS);
        u64*    skey  = (u64*)(ws + WS_SKEY);
        float4* sbox  = (float4*)(ws + WS_SBOX);
        float*  sarea = (float*)(ws + WS_SAREA);
        u64*    sup   = (u64*)(ws + WS_SUP);

        hipMemsetAsync(done, 0, 8, stream);
        kA_gather_sort<<<M_BOXES / 512, 512, 0, stream>>>(
            boxes_raw, scores, indices, p_out_h, p_out_w, out,
            vkeys, wcnt, done, pV, skey, sbox, sarea);
        kB_matrix_scan<<<(VCAP / 8) * NW / 8, 512, 0, stream>>>(
            out, skey, sbox, sarea, pV, sup, done);
    } else {
        int*    vcount = (int*)ws;
        u64*    vkeys  = (u64*)(ws + 16);
        float4* vboxes = (float4*)(ws + 16 + VCAP * sizeof(u64));
        hipMemsetAsync(d_ws, 0, 16, stream);
        fb_gather<<<M_BOXES / 256, 256, 0, stream>>>(
            boxes_raw, scores, indices, p_out_h, p_out_w, out,
            vkeys, vboxes, vcount);
        fb_nms<<<1, 1024, 0, stream>>>(out, vkeys, vboxes, vcount);
    }
}

// Round 8
// 38.577 us; speedup vs baseline: 1.9428x; 1.1437x over previous
//
#include <hip/hip_runtime.h>
#include <stdint.h>

#define M_BOXES 8192
#define MIN_CONF_F 0.25f
#define MIN_IOU_F 0.45f
#define VCAP 640          // ~19 sigma above E[valid]=307
#define NW 10             // VCAP/64 words per suppression row

typedef unsigned long long u64;
typedef unsigned int u32;

// ws layout (bytes) — nothing here requires initialization
#define WS_V      8        // int
#define WS_WCNT   64       // int[128]
#define WS_VKEYS  1024     // u64[8192] chunk-compacted keys
#define WS_SKEY   66560    // u64[VCAP]
#define WS_SBOX   71680    // float4[VCAP]
#define WS_SAREA  81920    // float[VCAP]
#define WS_SUP    84480    // u64[VCAP*NW]
#define WS_NEED   135680

__device__ inline float scalar_to_float(const int* p) {
    int v = p[0];
    if (v > 0 && v < (1 << 20)) return (float)v;   // plain int
    return __int_as_float(v);                      // float bit-pattern
}

__device__ inline u64 rl64(u64 v, int b) {
    u32 lo = (u32)__builtin_amdgcn_readlane((int)(u32)v, b);
    u32 hi = (u32)__builtin_amdgcn_readlane((int)(u32)(v >> 32), b);
    return ((u64)hi << 32) | lo;
}

__device__ inline u64 wave_or64(u64 v) {
    #pragma unroll
    for (int o = 32; o > 0; o >>= 1) {
        int lo = __shfl_xor((int)(u32)v, o, 64);
        int hi = __shfl_xor((int)(u32)(v >> 32), o, 64);
        v |= ((u64)(u32)hi << 32) | (u32)lo;
    }
    return v;
}

// ---- kA: fill output + gather + wave-ballot chunk compact (no atomics) ---
__global__ __launch_bounds__(512) void kA_gather(
    const float* __restrict__ scores, const int* __restrict__ indices,
    float* __restrict__ out, u64* __restrict__ vkeys, int* __restrict__ wcnt)
{
    int tid = threadIdx.x;
    int i = blockIdx.x * 512 + tid;                // grid covers exactly 8192
    int cls = indices[3 * i + 1];
    int idx = indices[3 * i + 2];
    float conf = scores[cls * M_BOXES + idx];
    *reinterpret_cast<float4*>(out + 4 * i) = make_float4(0.f, 0.f, 0.f, 0.f);
    out[4 * M_BOXES + i] = 0.f;
    out[5 * M_BOXES + i] = (float)cls;
    out[6 * M_BOXES + i] = 0.f;
    bool valid = (conf > MIN_CONF_F) &&
                 (cls == 2 || cls == 3 || cls == 5 || cls == 7);
    u64 mask = __ballot(valid);
    int lane = tid & 63;
    int wid = i >> 6;
    if (valid) {
        int pos = (int)__popcll(mask & ((1ull << lane) - 1ull));
        // key: [~conf:32][i:13][idx:13] -> conf desc, i asc (stable argsort)
        u64 key = ((u64)(~__float_as_uint(conf)) << 32)
                | ((u64)(u32)i << 13) | (u64)(u32)idx;
        vkeys[(wid << 6) + pos] = key;
    }
    if (lane == 0) wcnt[wid] = (int)__popcll(mask);
}

// ---- kS: single block; prefix + pipelined assembly + 512-wide rank sort --
__global__ __launch_bounds__(512) void kS_sort(
    const float* __restrict__ boxes_raw, const int* __restrict__ p_out_h,
    const int* __restrict__ p_out_w, const u64* __restrict__ vkeys,
    const int* __restrict__ wcnt, int* __restrict__ pV,
    u64* __restrict__ skey, float4* __restrict__ sbox,
    float* __restrict__ sarea)
{
    __shared__ int pre_s[129];
    __shared__ u64 tkey[VCAP];
    int tid = threadIdx.x;

    // prefix over 128 wave counts (two-halves shuffle scan on wave 0)
    if (tid < 64) {
        int cA = wcnt[tid], cB = wcnt[64 + tid];
        int sA = cA, sB = cB;
        #pragma unroll
        for (int o = 1; o < 64; o <<= 1) {
            int t = __shfl_up(sA, o, 64); if (tid >= o) sA += t;
            int u = __shfl_up(sB, o, 64); if (tid >= o) sB += u;
        }
        int totA = __shfl(sA, 63, 64);
        int totB = __shfl(sB, 63, 64);
        pre_s[tid] = sA - cA;
        pre_s[64 + tid] = totA + sB - cB;
        if (tid == 0) pre_s[128] = totA + totB;
    }
    __syncthreads();
    int V = pre_s[128];
    if (V > VCAP) V = VCAP;
    if (tid == 0) *pV = V;
    if (V <= 0) return;

    // assembly: one independent pipelined load per slot (binary search)
    for (int s = tid; s < V; s += 512) {
        int lo = 0, hi = 128;
        #pragma unroll
        for (int st = 0; st < 7; ++st) {
            int mid = (lo + hi) >> 1;
            if (pre_s[mid] <= s) lo = mid; else hi = mid;
        }
        tkey[s] = vkeys[(lo << 6) + (s - pre_s[lo])];
    }
    __syncthreads();

    // rank sort (unique keys -> permutation); gather + clip box per slot
    float W = scalar_to_float(p_out_w);
    float H = scalar_to_float(p_out_h);
    for (int s = tid; s < V; s += 512) {
        u64 k = tkey[s];
        int r = 0;
        #pragma unroll 4
        for (int j = 0; j < V; ++j) r += (tkey[j] < k) ? 1 : 0;
        int bidx = (int)(k & 0x1FFFull);
        float4 b = *reinterpret_cast<const float4*>(boxes_raw + 4 * bidx); // y1,x1,y2,x2
        float4 c4;
        c4.x = fminf(fmaxf(b.y, 0.f), W);
        c4.y = fminf(fmaxf(b.x, 0.f), H);
        c4.z = fminf(fmaxf(b.w, 0.f), W);
        c4.w = fminf(fmaxf(b.z, 0.f), H);
        skey[r] = k;
        sbox[r] = c4;
        sarea[r] = fmaxf(c4.z - c4.x, 0.f) * fmaxf(c4.w - c4.y, 0.f);
    }
}

// ---- kM: suppression bit-matrix, one (8-row x 64-col word) task per wave -
__global__ __launch_bounds__(512) void kM_matrix(
    const float4* __restrict__ sbox, const float* __restrict__ sarea,
    const int* __restrict__ pV, u64* __restrict__ sup)
{
    int V = *pV;
    int nw = (V + 63) >> 6;
    int wave = (blockIdx.x * 512 + threadIdx.x) >> 6;
    int lane = threadIdx.x & 63;
    int bi = wave / NW;                 // constant divisor -> magic mul
    int w = wave - bi * NW;
    int i0 = bi << 3;
    if (i0 >= V || w >= nw) return;
    int j = (w << 6) + lane;
    bool jv = j < V;
    float4 bj = jv ? sbox[j] : make_float4(0.f, 0.f, 0.f, 0.f);
    float aj = jv ? sarea[j] : 0.f;
    int rend = V - i0; if (rend > 8) rend = 8;
    for (int r = 0; r < rend; ++r) {
        int i = i0 + r;
        float4 bi4 = sbox[i];           // uniform
        float ai = sarea[i];            // uniform
        bool p = false;
        if (jv && j > i) {
            float ix1 = fmaxf(bi4.x, bj.x);
            float iy1 = fmaxf(bi4.y, bj.y);
            float ix2 = fminf(bi4.z, bj.z);
            float iy2 = fminf(bi4.w, bj.w);
            float inter = fmaxf(ix2 - ix1, 0.f) * fmaxf(iy2 - iy1, 0.f);
            float iou = inter / (ai + aj - inter + 1e-9f);   // IEEE div
            p = iou > MIN_IOU_F;
        }
        u64 bits = __ballot(p);
        if (lane == 0) sup[i * NW + w] = bits;
    }
}

// ---- kZ: single-wave branchless scan + scatter ---------------------------
__global__ __launch_bounds__(64) void kZ_scan_scatter(
    float* __restrict__ out, const u64* __restrict__ skey,
    const float4* __restrict__ sbox, const int* __restrict__ pV,
    const u64* __restrict__ supG)
{
    int lane = threadIdx.x;
    int V = *pV;
    if (V <= 0) return;
    int nw = (V + 63) >> 6;

    u64 live[NW], supp[NW];
    #pragma unroll
    for (int w = 0; w < NW; ++w) {
        int c = V - (w << 6);
        live[w] = (c >= 64) ? ~0ull : (c > 0 ? ((1ull << c) - 1ull) : 0ull);
        supp[w] = 0ull;
    }

    u64 rowA[NW], rowB[NW];
    {   // load chunk 0 rows
        bool rv = lane < V;
        #pragma unroll
        for (int w = 0; w < NW; ++w)
            rowA[w] = (rv && w < nw) ? supG[lane * NW + w] : 0ull;
    }

    auto step = [&](u64 (&rc)[NW], u64 (&rn)[NW], int ci) {
        // prefetch chunk ci+1 (words >= ci+1 only)
        int rI = ((ci + 1) << 6) + lane;
        bool rv = (ci + 1) < nw && rI < V;
        #pragma unroll
        for (int w = 0; w < NW; ++w)
            rn[w] = (rv && w >= ci + 1 && w < nw) ? supG[rI * NW + w] : 0ull;
        // select diagonal word + init (static reg indices, runtime guard)
        u64 rw = 0, cur = 0;
        #pragma unroll
        for (int w = 0; w < NW; ++w)
            if (w == ci) { rw = rc[w]; cur = live[w] & ~supp[w]; }
        // 64-step branchless in-word recurrence
        #pragma unroll
        for (int b = 0; b < 64; ++b) {
            u64 rb = rl64(rw, b);
            u64 nxt = cur & ~rb;            // row has only bits > b
            cur = ((cur >> b) & 1ull) ? nxt : cur;
        }
        #pragma unroll
        for (int w = 0; w < NW; ++w) if (w == ci) live[w] = cur;
        // cross-word suppression, once per future word
        #pragma unroll
        for (int w2 = 0; w2 < NW; ++w2)
            if (w2 > ci && w2 < nw) {
                u64 mine = ((cur >> lane) & 1ull) ? rc[w2] : 0ull;
                supp[w2] |= wave_or64(mine);
            }
    };

    int ci = 0;
    while (ci < nw) {
        step(rowA, rowB, ci); ++ci;
        if (ci < nw) { step(rowB, rowA, ci); ++ci; }
    }

    // scatter kept entries
    #pragma unroll
    for (int ii = 0; ii < NW; ++ii) {
        int s = (ii << 6) + lane;
        if ((ii << 6) < V && s < V && ((live[ii] >> lane) & 1ull)) {
            u64 k = skey[s];
            u32 orig = (u32)((k >> 13) & 0x1FFFull);
            float conf = __uint_as_float(~(u32)(k >> 32));   // exact roundtrip
            float4 b = sbox[s];
            *reinterpret_cast<float4*>(out + 4 * orig) = b;
            out[4 * M_BOXES + orig] = conf;
            out[6 * M_BOXES + orig] = 1.0f;
        }
    }
}

// ---------------- fallback (small ws): atomic compaction path -------------
__global__ __launch_bounds__(256) void fb_gather(
    const float* __restrict__ boxes_raw, const float* __restrict__ scores,
    const int* __restrict__ indices, const int* __restrict__ p_out_h,
    const int* __restrict__ p_out_w, float* __restrict__ out,
    u64* __restrict__ vkeys, float4* __restrict__ vboxes,
    int* __restrict__ vcount)
{
    int i = blockIdx.x * blockDim.x + threadIdx.x;
    if (i >= M_BOXES) return;
    int cls = indices[3 * i + 1];
    int idx = indices[3 * i + 2];
    float conf = scores[cls * M_BOXES + idx];
    *reinterpret_cast<float4*>(out + 4 * i) = make_float4(0.f, 0.f, 0.f, 0.f);
    out[4 * M_BOXES + i] = 0.f;
    out[5 * M_BOXES + i] = (float)cls;
    out[6 * M_BOXES + i] = 0.f;
    bool valid = (conf > MIN_CONF_F) &&
                 (cls == 2 || cls == 3 || cls == 5 || cls == 7);
    if (valid) {
        float4 b = *reinterpret_cast<const float4*>(boxes_raw + 4 * idx);
        float W = scalar_to_float(p_out_w);
        float H = scalar_to_float(p_out_h);
        float4 c;
        c.x = fminf(fmaxf(b.y, 0.f), W);
        c.y = fminf(fmaxf(b.x, 0.f), H);
        c.z = fminf(fmaxf(b.w, 0.f), W);
        c.w = fminf(fmaxf(b.z, 0.f), H);
        int p = atomicAdd(vcount, 1);
        if (p < VCAP) {
            vkeys[p] = ((u64)(~__float_as_uint(conf)) << 32) | (u32)i;
            vboxes[p] = c;
        }
    }
}

__global__ __launch_bounds__(1024) void fb_nms(
    float* __restrict__ out, const u64* __restrict__ vkeys,
    const float4* __restrict__ vboxes, const int* __restrict__ vcount)
{
    __shared__ u64 tkey[VCAP];
    __shared__ u64 skey[VCAP];
    __shared__ float4 sbox[VCAP];
    __shared__ unsigned char keepb[VCAP];
    int tid = threadIdx.x;
    int V = *vcount;
    if (V > VCAP) V = VCAP;
    if (V <= 0) return;
    for (int s = tid; s < V; s += 1024) tkey[s] = vkeys[s];
    __syncthreads();
    for (int s = tid; s < V; s += 1024) {
        u64 k = tkey[s];
        int r = 0;
        for (int j = 0; j < V; ++j) r += (tkey[j] < k);
        skey[r] = k;
        sbox[r] = vboxes[s];
    }
    __syncthreads();
    for (int s = tid; s < V; s += 1024) keepb[s] = 1;
    __syncthreads();
    for (int i = 0; i < V; ++i) {
        if (keepb[i]) {
            float4 bi = sbox[i];
            float ai = fmaxf(bi.z - bi.x, 0.f) * fmaxf(bi.w - bi.y, 0.f);
            for (int s = i + 1 + tid; s < V; s += 1024) {
                if (keepb[s]) {
                    float4 bj = sbox[s];
                    float aj = fmaxf(bj.z - bj.x, 0.f) * fmaxf(bj.w - bj.y, 0.f);
                    float ix1 = fmaxf(bi.x, bj.x);
                    float iy1 = fmaxf(bi.y, bj.y);
                    float ix2 = fminf(bi.z, bj.z);
                    float iy2 = fminf(bi.w, bj.w);
                    float inter = fmaxf(ix2 - ix1, 0.f) * fmaxf(iy2 - iy1, 0.f);
                    float iou = inter / (ai + aj - inter + 1e-9f);
                    if (iou > MIN_IOU_F) keepb[s] = 0;
                }
            }
        }
        __syncthreads();
    }
    for (int s = tid; s < V; s += 1024) {
        if (keepb[s]) {
            u64 k = skey[s];
            u32 orig = (u32)(k & 0xFFFFFFFFull);
            float conf = __uint_as_float(~(u32)(k >> 32));
            float4 b = sbox[s];
            *reinterpret_cast<float4*>(out + 4 * orig) = b;
            out[4 * M_BOXES + orig] = conf;
            out[6 * M_BOXES + orig] = 1.0f;
        }
    }
}

extern "C" void kernel_launch(void* const* d_in, const int* in_sizes, int n_in,
                              void* d_out, int out_size, void* d_ws, size_t ws_size,
                              hipStream_t stream) {
    const float* boxes_raw = (const float*)d_in[0];
    const float* scores    = (const float*)d_in[1];
    const int*   indices   = (const int*)d_in[2];
    const int*   p_out_h   = (const int*)d_in[3];
    const int*   p_out_w   = (const int*)d_in[4];
    float* out = (float*)d_out;
    char* ws = (char*)d_ws;

    if (ws_size >= WS_NEED) {
        int*    pV    = (int*)(ws + WS_V);
        int*    wcnt  = (int*)(ws + WS_WCNT);
        u64*    vkeys = (u64*)(ws + WS_VKEYS);
        u64*    skey  = (u64*)(ws + WS_SKEY);
        float4* sbox  = (float4*)(ws + WS_SBOX);
        float*  sarea = (float*)(ws + WS_SAREA);
        u64*    sup   = (u64*)(ws + WS_SUP);

        kA_gather<<<M_BOXES / 512, 512, 0, stream>>>(
            scores, indices, out, vkeys, wcnt);
        kS_sort<<<1, 512, 0, stream>>>(
            boxes_raw, p_out_h, p_out_w, vkeys, wcnt, pV, skey, sbox, sarea);
        kM_matrix<<<(VCAP / 8) * NW / 8, 512, 0, stream>>>(
            sbox, sarea, pV, sup);
        kZ_scan_scatter<<<1, 64, 0, stream>>>(out, skey, sbox, pV, sup);
    } else {
        int*    vcount = (int*)ws;
        u64*    vkeys  = (u64*)(ws + 16);
        float4* vboxes = (float4*)(ws + 16 + VCAP * sizeof(u64));
        hipMemsetAsync(d_ws, 0, 16, stream);
        fb_gather<<<M_BOXES / 256, 256, 0, stream>>>(
            boxes_raw, scores, indices, p_out_h, p_out_w, out,
            vkeys, vboxes, vcount);
        fb_nms<<<1, 1024, 0, stream>>>(out, vkeys, vboxes, vcount);
    }
}

// Round 9
// 37.669 us; speedup vs baseline: 1.9897x; 1.0241x over previous
//
#include <hip/hip_runtime.h>
#include <stdint.h>

#define M_BOXES 8192
#define MIN_CONF_F 0.25f
#define MIN_IOU_F 0.45f
#define VCAP 640          // ~19 sigma above E[valid]=307
#define NW 10             // VCAP/64 words per suppression row
#define NBLK 16

typedef unsigned long long u64;
typedef unsigned int u32;

// ws layout (bytes); cnt[2] zeroed by kA each call (stream-ordered)
#define WS_CNT    0        // int[2] barrier counters
#define WS_WCNT   64       // int[128]
#define WS_VKEYS  1024     // u64[8192] chunk-compacted keys
#define WS_SKEY   66560    // u64[VCAP]
#define WS_SBOX   71680    // float4[VCAP]
#define WS_SAREA  81920    // float[VCAP]
#define WS_SUP    84480    // u64[VCAP*NW]
#define WS_NEED   135680

__device__ inline float scalar_to_float(const int* p) {
    int v = p[0];
    if (v > 0 && v < (1 << 20)) return (float)v;   // plain int
    return __int_as_float(v);                      // float bit-pattern
}

__device__ inline u64 rl64(u64 v, int b) {
    u32 lo = (u32)__builtin_amdgcn_readlane((int)(u32)v, b);
    u32 hi = (u32)__builtin_amdgcn_readlane((int)(u32)(v >> 32), b);
    return ((u64)hi << 32) | lo;
}

__device__ inline u64 wave_or64(u64 v) {
    #pragma unroll
    for (int o = 32; o > 0; o >>= 1) {
        int lo = __shfl_xor((int)(u32)v, o, 64);
        int hi = __shfl_xor((int)(u32)(v >> 32), o, 64);
        v |= ((u64)(u32)hi << 32) | (u32)lo;
    }
    return v;
}

// device-scope spin barrier; counters pre-zeroed by kA (16 co-resident blocks)
__device__ inline void grid_bar(int* c, int nblk) {
    __syncthreads();
    if (threadIdx.x == 0) {
        __hip_atomic_fetch_add(c, 1, __ATOMIC_ACQ_REL, __HIP_MEMORY_SCOPE_AGENT);
        while (__hip_atomic_load(c, __ATOMIC_ACQUIRE, __HIP_MEMORY_SCOPE_AGENT) < nblk)
            __builtin_amdgcn_s_sleep(1);
    }
    __syncthreads();
}

// ---- kA: fill output + gather + wave-ballot chunk compact; zero counters -
__global__ __launch_bounds__(512) void kA_gather(
    const float* __restrict__ scores, const int* __restrict__ indices,
    float* __restrict__ out, u64* __restrict__ vkeys, int* __restrict__ wcnt,
    int* __restrict__ cnt)
{
    int tid = threadIdx.x;
    int i = blockIdx.x * 512 + tid;                // grid covers exactly 8192
    if (i == 0) { cnt[0] = 0; cnt[1] = 0; }
    int cls = indices[3 * i + 1];
    int idx = indices[3 * i + 2];
    float conf = scores[cls * M_BOXES + idx];
    *reinterpret_cast<float4*>(out + 4 * i) = make_float4(0.f, 0.f, 0.f, 0.f);
    out[4 * M_BOXES + i] = 0.f;
    out[5 * M_BOXES + i] = (float)cls;
    out[6 * M_BOXES + i] = 0.f;
    bool valid = (conf > MIN_CONF_F) &&
                 (cls == 2 || cls == 3 || cls == 5 || cls == 7);
    u64 mask = __ballot(valid);
    int lane = tid & 63;
    int wid = i >> 6;
    if (valid) {
        int pos = (int)__popcll(mask & ((1ull << lane) - 1ull));
        // key: [~conf:32][i:13][idx:13] -> conf desc, i asc (stable argsort)
        u64 key = ((u64)(~__float_as_uint(conf)) << 32)
                | ((u64)(u32)i << 13) | (u64)(u32)idx;
        vkeys[(wid << 6) + pos] = key;
    }
    if (lane == 0) wcnt[wid] = (int)__popcll(mask);
}

// ---- kMEGA: sort (distributed) | barrier | matrix | barrier | scan -------
__global__ __launch_bounds__(512) void kMEGA(
    const float* __restrict__ boxes_raw, const int* __restrict__ p_out_h,
    const int* __restrict__ p_out_w, float* __restrict__ out,
    const u64* __restrict__ vkeys, const int* __restrict__ wcnt,
    u64* __restrict__ skey, float4* __restrict__ sbox,
    float* __restrict__ sarea, u64* __restrict__ sup, int* __restrict__ cnt)
{
    __shared__ int pre_s[129];
    __shared__ u64 tkey[VCAP];
    __shared__ u64 live_s[NW];
    int tid = threadIdx.x;
    int widx = tid >> 6, lane = tid & 63;

    // ---- phase S: prefix (redundant per block) + assembly + wave-rank sort
    if (tid < 64) {
        int cA = wcnt[tid], cB = wcnt[64 + tid];
        int sA = cA, sB = cB;
        #pragma unroll
        for (int o = 1; o < 64; o <<= 1) {
            int t = __shfl_up(sA, o, 64); if (tid >= o) sA += t;
            int u = __shfl_up(sB, o, 64); if (tid >= o) sB += u;
        }
        int totA = __shfl(sA, 63, 64);
        int totB = __shfl(sB, 63, 64);
        pre_s[tid] = sA - cA;
        pre_s[64 + tid] = totA + sB - cB;
        if (tid == 0) pre_s[128] = totA + totB;
    }
    __syncthreads();
    int V = pre_s[128];
    if (V > VCAP) V = VCAP;

    if (V > 0) {
        // assembly: one independent pipelined load per slot (binary search)
        for (int s = tid; s < V; s += 512) {
            int lo = 0, hi = 128;
            #pragma unroll
            for (int st = 0; st < 7; ++st) {
                int mid = (lo + hi) >> 1;
                if (pre_s[mid] <= s) lo = mid; else hi = mid;
            }
            tkey[s] = vkeys[(lo << 6) + (s - pre_s[lo])];
        }
        __syncthreads();

        // wave-parallel rank sort: each wave owns a slot; lanes partial-count
        float W = scalar_to_float(p_out_w);
        float H = scalar_to_float(p_out_h);
        int spb = (V + NBLK - 1) / NBLK;         // slots per block
        int s0 = blockIdx.x * spb;
        int send = s0 + spb; if (send > V) send = V;
        for (int s = s0 + widx; s < send; s += 8) {
            u64 k = tkey[s];
            int r = 0;
            for (int j = lane; j < V; j += 64) r += (tkey[j] < k) ? 1 : 0;
            #pragma unroll
            for (int o = 1; o < 64; o <<= 1) r += __shfl_xor(r, o, 64);
            if (lane == 0) {
                int bidx = (int)(k & 0x1FFFull);
                float4 b = *reinterpret_cast<const float4*>(boxes_raw + 4 * bidx);
                float4 c4;                       // b = y1,x1,y2,x2
                c4.x = fminf(fmaxf(b.y, 0.f), W);
                c4.y = fminf(fmaxf(b.x, 0.f), H);
                c4.z = fminf(fmaxf(b.w, 0.f), W);
                c4.w = fminf(fmaxf(b.z, 0.f), H);
                skey[r] = k;
                sbox[r] = c4;
                sarea[r] = fmaxf(c4.z - c4.x, 0.f) * fmaxf(c4.w - c4.y, 0.f);
            }
        }
    }
    grid_bar(&cnt[0], NBLK);

    // ---- phase M: suppression bit-matrix, tasks strided over 128 waves ---
    if (V > 0) {
        int nw = (V + 63) >> 6;
        int nbi = (V + 7) >> 3;
        int ntask = nbi * nw;
        int gwave = blockIdx.x * 8 + widx;
        for (int t = gwave; t < ntask; t += NBLK * 8) {
            int bi = t / nw;
            int w = t - bi * nw;
            int i0 = bi << 3;
            int j = (w << 6) + lane;
            bool jv = j < V;
            float4 bj = jv ? sbox[j] : make_float4(0.f, 0.f, 0.f, 0.f);
            float aj = jv ? sarea[j] : 0.f;
            int rend = V - i0; if (rend > 8) rend = 8;
            for (int r = 0; r < rend; ++r) {
                int i = i0 + r;
                float4 bi4 = sbox[i];            // uniform
                float ai = sarea[i];             // uniform
                bool p = false;
                if (jv && j > i) {
                    float ix1 = fmaxf(bi4.x, bj.x);
                    float iy1 = fmaxf(bi4.y, bj.y);
                    float ix2 = fminf(bi4.z, bj.z);
                    float iy2 = fminf(bi4.w, bj.w);
                    float inter = fmaxf(ix2 - ix1, 0.f) * fmaxf(iy2 - iy1, 0.f);
                    float iou = inter / (ai + aj - inter + 1e-9f);  // IEEE div
                    p = iou > MIN_IOU_F;
                }
                u64 bits = __ballot(p);
                if (lane == 0) sup[i * NW + w] = bits;
            }
        }
    }
    grid_bar(&cnt[1], NBLK);

    // ---- phase Z: block 0: branchless readlane scan + scatter ------------
    if (blockIdx.x != 0 || V <= 0) return;
    int nw = (V + 63) >> 6;
    if (tid < 64) {
        u64 live[NW], supp[NW];
        #pragma unroll
        for (int w = 0; w < NW; ++w) {
            int c = V - (w << 6);
            live[w] = (c >= 64) ? ~0ull : (c > 0 ? ((1ull << c) - 1ull) : 0ull);
            supp[w] = 0ull;
        }
        u64 rowA[NW], rowB[NW];
        {
            bool rv = lane < V;
            #pragma unroll
            for (int w = 0; w < NW; ++w)
                rowA[w] = (rv && w < nw) ? sup[lane * NW + w] : 0ull;
        }
        auto step = [&](u64 (&rc)[NW], u64 (&rn)[NW], int ci) {
            int rI = ((ci + 1) << 6) + lane;
            bool rv = (ci + 1) < nw && rI < V;
            #pragma unroll
            for (int w = 0; w < NW; ++w)
                rn[w] = (rv && w >= ci + 1 && w < nw) ? sup[rI * NW + w] : 0ull;
            u64 rw = 0, cur = 0;
            #pragma unroll
            for (int w = 0; w < NW; ++w)
                if (w == ci) { rw = rc[w]; cur = live[w] & ~supp[w]; }
            #pragma unroll
            for (int b = 0; b < 64; ++b) {
                u64 rb = rl64(rw, b);
                u64 nxt = cur & ~rb;            // row has only bits > b
                cur = ((cur >> b) & 1ull) ? nxt : cur;
            }
            #pragma unroll
            for (int w = 0; w < NW; ++w) if (w == ci) live[w] = cur;
            #pragma unroll
            for (int w2 = 0; w2 < NW; ++w2)
                if (w2 > ci && w2 < nw) {
                    u64 mine = ((cur >> lane) & 1ull) ? rc[w2] : 0ull;
                    supp[w2] |= wave_or64(mine);
                }
        };
        int ci = 0;
        while (ci < nw) {
            step(rowA, rowB, ci); ++ci;
            if (ci < nw) { step(rowB, rowA, ci); ++ci; }
        }
        #pragma unroll
        for (int w = 0; w < NW; ++w) live_s[w] = live[w];   // lane-uniform
    }
    __syncthreads();
    for (int s = tid; s < V; s += 512) {
        if ((live_s[s >> 6] >> (s & 63)) & 1ull) {
            u64 k = skey[s];
            u32 orig = (u32)((k >> 13) & 0x1FFFull);
            float conf = __uint_as_float(~(u32)(k >> 32));   // exact roundtrip
            float4 b = sbox[s];
            *reinterpret_cast<float4*>(out + 4 * orig) = b;
            out[4 * M_BOXES + orig] = conf;
            out[6 * M_BOXES + orig] = 1.0f;
        }
    }
}

// ---------------- fallback (small ws): atomic compaction path -------------
__global__ __launch_bounds__(256) void fb_gather(
    const float* __restrict__ boxes_raw, const float* __restrict__ scores,
    const int* __restrict__ indices, const int* __restrict__ p_out_h,
    const int* __restrict__ p_out_w, float* __restrict__ out,
    u64* __restrict__ vkeys, float4* __restrict__ vboxes,
    int* __restrict__ vcount)
{
    int i = blockIdx.x * blockDim.x + threadIdx.x;
    if (i >= M_BOXES) return;
    int cls = indices[3 * i + 1];
    int idx = indices[3 * i + 2];
    float conf = scores[cls * M_BOXES + idx];
    *reinterpret_cast<float4*>(out + 4 * i) = make_float4(0.f, 0.f, 0.f, 0.f);
    out[4 * M_BOXES + i] = 0.f;
    out[5 * M_BOXES + i] = (float)cls;
    out[6 * M_BOXES + i] = 0.f;
    bool valid = (conf > MIN_CONF_F) &&
                 (cls == 2 || cls == 3 || cls == 5 || cls == 7);
    if (valid) {
        float4 b = *reinterpret_cast<const float4*>(boxes_raw + 4 * idx);
        float W = scalar_to_float(p_out_w);
        float H = scalar_to_float(p_out_h);
        float4 c;
        c.x = fminf(fmaxf(b.y, 0.f), W);
        c.y = fminf(fmaxf(b.x, 0.f), H);
        c.z = fminf(fmaxf(b.w, 0.f), W);
        c.w = fminf(fmaxf(b.z, 0.f), H);
        int p = atomicAdd(vcount, 1);
        if (p < VCAP) {
            vkeys[p] = ((u64)(~__float_as_uint(conf)) << 32) | (u32)i;
            vboxes[p] = c;
        }
    }
}

__global__ __launch_bounds__(1024) void fb_nms(
    float* __restrict__ out, const u64* __restrict__ vkeys,
    const float4* __restrict__ vboxes, const int* __restrict__ vcount)
{
    __shared__ u64 tkey[VCAP];
    __shared__ u64 skey[VCAP];
    __shared__ float4 sbox[VCAP];
    __shared__ unsigned char keepb[VCAP];
    int tid = threadIdx.x;
    int V = *vcount;
    if (V > VCAP) V = VCAP;
    if (V <= 0) return;
    for (int s = tid; s < V; s += 1024) tkey[s] = vkeys[s];
    __syncthreads();
    for (int s = tid; s < V; s += 1024) {
        u64 k = tkey[s];
        int r = 0;
        for (int j = 0; j < V; ++j) r += (tkey[j] < k);
        skey[r] = k;
        sbox[r] = vboxes[s];
    }
    __syncthreads();
    for (int s = tid; s < V; s += 1024) keepb[s] = 1;
    __syncthreads();
    for (int i = 0; i < V; ++i) {
        if (keepb[i]) {
            float4 bi = sbox[i];
            float ai = fmaxf(bi.z - bi.x, 0.f) * fmaxf(bi.w - bi.y, 0.f);
            for (int s = i + 1 + tid; s < V; s += 1024) {
                if (keepb[s]) {
                    float4 bj = sbox[s];
                    float aj = fmaxf(bj.z - bj.x, 0.f) * fmaxf(bj.w - bj.y, 0.f);
                    float ix1 = fmaxf(bi.x, bj.x);
                    float iy1 = fmaxf(bi.y, bj.y);
                    float ix2 = fminf(bi.z, bj.z);
                    float iy2 = fminf(bi.w, bj.w);
                    float inter = fmaxf(ix2 - ix1, 0.f) * fmaxf(iy2 - iy1, 0.f);
                    float iou = inter / (ai + aj - inter + 1e-9f);
                    if (iou > MIN_IOU_F) keepb[s] = 0;
                }
            }
        }
        __syncthreads();
    }
    for (int s = tid; s < V; s += 1024) {
        if (keepb[s]) {
            u64 k = skey[s];
            u32 orig = (u32)(k & 0xFFFFFFFFull);
            float conf = __uint_as_float(~(u32)(k >> 32));
            float4 b = sbox[s];
            *reinterpret_cast<float4*>(out + 4 * orig) = b;
            out[4 * M_BOXES + orig] = conf;
            out[6 * M_BOXES + orig] = 1.0f;
        }
    }
}

extern "C" void kernel_launch(void* const* d_in, const int* in_sizes, int n_in,
                              void* d_out, int out_size, void* d_ws, size_t ws_size,
                              hipStream_t stream) {
    const float* boxes_raw = (const float*)d_in[0];
    const float* scores    = (const float*)d_in[1];
    const int*   indices   = (const int*)d_in[2];
    const int*   p_out_h   = (const int*)d_in[3];
    const int*   p_out_w   = (const int*)d_in[4];
    float* out = (float*)d_out;
    char* ws = (char*)d_ws;

    if (ws_size >= WS_NEED) {
        int*    cnt   = (int*)(ws + WS_CNT);
        int*    wcnt  = (int*)(ws + WS_WCNT);
        u64*    vkeys = (u64*)(ws + WS_VKEYS);
        u64*    skey  = (u64*)(ws + WS_SKEY);
        float4* sbox  = (float4*)(ws + WS_SBOX);
        float*  sarea = (float*)(ws + WS_SAREA);
        u64*    sup   = (u64*)(ws + WS_SUP);

        kA_gather<<<M_BOXES / 512, 512, 0, stream>>>(
            scores, indices, out, vkeys, wcnt, cnt);
        kMEGA<<<NBLK, 512, 0, stream>>>(
            boxes_raw, p_out_h, p_out_w, out, vkeys, wcnt,
            skey, sbox, sarea, sup, cnt);
    } else {
        int*    vcount = (int*)ws;
        u64*    vkeys  = (u64*)(ws + 16);
        float4* vboxes = (float4*)(ws + 16 + VCAP * sizeof(u64));
        hipMemsetAsync(d_ws, 0, 16, stream);
        fb_gather<<<M_BOXES / 256, 256, 0, stream>>>(
            boxes_raw, scores, indices, p_out_h, p_out_w, out,
            vkeys, vboxes, vcount);
        fb_nms<<<1, 1024, 0, stream>>>(out, vkeys, vboxes, vcount);
    }
}